// Round 1
// baseline (1043.156 us; speedup 1.0000x reference)
//
#include <hip/hip_runtime.h>
#include <hip/hip_bf16.h>

// Model dims
#define VOCAB 21128
#define EMBED 768
#define DMODEL 256
#define HID 100
#define NTAGS 21
#define BB 32
#define TT 256
#define NTOK (BB*TT)   // 8192 tokens, token index i = t*BB + b

__device__ __forceinline__ float sigm(float x) { return 1.0f / (1.0f + __expf(-x)); }
__device__ __forceinline__ float tanh_(float x) { return 2.0f / (1.0f + __expf(-2.0f * x)) - 1.0f; }

// ---------------------------------------------------------------------------
// Generic SGEMM: C(M x N) = A(M x K) @ B(N x K)^T + bias1 + bias2
// A rows optionally gathered through the embedding: row i -> embed row
// words[(i&31)*TT + (i>>5)].
// Tiles: 64x64, Ktile=8, 256 threads, 4x4 per-thread microtile.
// ---------------------------------------------------------------------------
__global__ __launch_bounds__(256) void gemm_bias(
    const float* __restrict__ A, int lda,
    const float* __restrict__ B, int ldb,
    const float* __restrict__ bias1, const float* __restrict__ bias2,
    float* __restrict__ C, int ldc,
    int M, int N, int K,
    const int* __restrict__ gatherWords)
{
    __shared__ float As[8][64];
    __shared__ float Bs[8][64];
    const int row0 = blockIdx.x * 64;
    const int col0 = blockIdx.y * 64;
    const int tid = threadIdx.x;
    const int tx = tid & 15;        // 0..15 -> cols
    const int ty = tid >> 4;        // 0..15 -> rows
    float acc[4][4] = {};

    for (int k0 = 0; k0 < K; k0 += 8) {
        if (tid < 128) {
            int r = tid >> 1, q = tid & 1;
            int grow = row0 + r;
            const float* ap;
            if (gatherWords) {
                int widx = gatherWords[(grow & 31) * TT + (grow >> 5)];
                ap = A + (size_t)widx * lda;
            } else {
                ap = A + (size_t)grow * lda;
            }
            float4 v = *(const float4*)(ap + k0 + q * 4);
            As[q*4+0][r] = v.x; As[q*4+1][r] = v.y;
            As[q*4+2][r] = v.z; As[q*4+3][r] = v.w;
        } else {
            int f = tid - 128;
            int r = f >> 1, q = f & 1;
            int gcol = col0 + r;
            float4 v = make_float4(0.f, 0.f, 0.f, 0.f);
            if (gcol < N) v = *(const float4*)(B + (size_t)gcol * ldb + k0 + q * 4);
            Bs[q*4+0][r] = v.x; Bs[q*4+1][r] = v.y;
            Bs[q*4+2][r] = v.z; Bs[q*4+3][r] = v.w;
        }
        __syncthreads();
        #pragma unroll
        for (int kk = 0; kk < 8; ++kk) {
            float4 av = *(const float4*)&As[kk][ty * 4];
            float4 bv = *(const float4*)&Bs[kk][tx * 4];
            acc[0][0] += av.x * bv.x; acc[0][1] += av.x * bv.y;
            acc[0][2] += av.x * bv.z; acc[0][3] += av.x * bv.w;
            acc[1][0] += av.y * bv.x; acc[1][1] += av.y * bv.y;
            acc[1][2] += av.y * bv.z; acc[1][3] += av.y * bv.w;
            acc[2][0] += av.z * bv.x; acc[2][1] += av.z * bv.y;
            acc[2][2] += av.z * bv.z; acc[2][3] += av.z * bv.w;
            acc[3][0] += av.w * bv.x; acc[3][1] += av.w * bv.y;
            acc[3][2] += av.w * bv.z; acc[3][3] += av.w * bv.w;
        }
        __syncthreads();
    }

    float bb_[4];
    #pragma unroll
    for (int jj = 0; jj < 4; ++jj) {
        int gcol = col0 + tx * 4 + jj;
        float bv = 0.f;
        if (gcol < N) {
            bv = bias1[gcol];
            if (bias2) bv += bias2[gcol];
        }
        bb_[jj] = bv;
    }
    #pragma unroll
    for (int ii = 0; ii < 4; ++ii) {
        int grow = row0 + ty * 4 + ii;
        #pragma unroll
        for (int jj = 0; jj < 4; ++jj) {
            int gcol = col0 + tx * 4 + jj;
            if (gcol < N) C[(size_t)grow * ldc + gcol] = acc[ii][jj] + bb_[jj];
        }
    }
}

// ---------------------------------------------------------------------------
// LSTM recurrence for one layer, both directions.
// grid = 64 blocks: block = (dir<<5)|b.  448 threads.
// pre: (NTOK, 800) with gate g of dir d at [i*800 + d*400 + g] (biases folded).
// Whh: (2, 400, 100).  hout: (NTOK, 200), dir0 -> [0..99], dir1 -> [100..199].
// ---------------------------------------------------------------------------
__global__ __launch_bounds__(448) void lstm_layer(
    const float* __restrict__ pre,
    const float* __restrict__ Whh,
    float* __restrict__ hout)
{
    const int dir = blockIdx.x >> 5;
    const int b = blockIdx.x & 31;
    const int tid = threadIdx.x;
    __shared__ alignas(16) float h_lds[HID];
    __shared__ float g_lds[4 * HID];

    float w[HID];
    if (tid < 400) {
        const float* wr = Whh + (size_t)dir * 400 * HID + (size_t)tid * HID;
        #pragma unroll
        for (int k = 0; k < HID; ++k) w[k] = wr[k];
    }
    float c = 0.f;
    if (tid < HID) h_lds[tid] = 0.f;
    __syncthreads();

    for (int s = 0; s < TT; ++s) {
        const int t = dir ? (TT - 1 - s) : s;
        const int i = t * BB + b;
        if (tid < 400) {
            float a0 = 0.f, a1 = 0.f, a2 = 0.f, a3 = 0.f;
            #pragma unroll
            for (int kk = 0; kk < HID / 4; ++kk) {
                float4 hv = *(const float4*)&h_lds[kk * 4];
                a0 += w[kk*4+0] * hv.x;
                a1 += w[kk*4+1] * hv.y;
                a2 += w[kk*4+2] * hv.z;
                a3 += w[kk*4+3] * hv.w;
            }
            g_lds[tid] = pre[(size_t)i * 800 + dir * 400 + tid] + ((a0 + a1) + (a2 + a3));
        }
        __syncthreads();
        if (tid < HID) {
            float ig = sigm(g_lds[tid]);
            float fg = sigm(g_lds[HID + tid]);
            float gg = tanh_(g_lds[2 * HID + tid]);
            float og = sigm(g_lds[3 * HID + tid]);
            c = fg * c + ig * gg;
            float h = og * tanh_(c);
            h_lds[tid] = h;
            hout[(size_t)i * 200 + dir * HID + tid] = h;
        }
        __syncthreads();
    }
}

// ---------------------------------------------------------------------------
// logits + log_softmax: per token i: l[n] = h1[i] . out_w[n] + out_b[n],
// then l -= logsumexp(l).  One 32-lane half-wave per token.
// ---------------------------------------------------------------------------
__global__ __launch_bounds__(256) void logits_lsm(
    const float* __restrict__ h1,
    const float* __restrict__ out_w,
    const float* __restrict__ out_b,
    float* __restrict__ logits)
{
    const int lane = threadIdx.x & 63;
    const int wid = (blockIdx.x * 256 + threadIdx.x) >> 6;
    const int half = lane >> 5;
    const int n = lane & 31;
    const int i = wid * 2 + half;
    if (i >= NTOK) return;

    float acc = -1e30f;
    if (n < NTAGS) {
        acc = out_b[n];
        const float* hr = h1 + (size_t)i * 200;
        const float* wr = out_w + (size_t)n * 200;
        for (int e = 0; e < 200; ++e) acc += hr[e] * wr[e];
    }
    float m = acc;
    for (int off = 16; off > 0; off >>= 1) m = fmaxf(m, __shfl_xor(m, off, 32));
    float ex = (n < NTAGS) ? __expf(acc - m) : 0.f;
    float s = ex;
    for (int off = 16; off > 0; off >>= 1) s += __shfl_xor(s, off, 32);
    if (n < NTAGS) logits[(size_t)i * NTAGS + n] = acc - m - __logf(s);
}

// ---------------------------------------------------------------------------
// CRF loss: one wave per batch element. alpha recursion + normalizer + gold.
// ---------------------------------------------------------------------------
__global__ __launch_bounds__(64) void crf_kernel(
    const float* __restrict__ logits,
    const int* __restrict__ words,
    const int* __restrict__ target,
    const float* __restrict__ trans,
    const float* __restrict__ start_s,
    const float* __restrict__ end_s,
    float* __restrict__ out)
{
    const int b = blockIdx.x;
    const int j = threadIdx.x;

    float tcol[NTAGS];
    #pragma unroll
    for (int i = 0; i < NTAGS; ++i) tcol[i] = (j < NTAGS) ? trans[i * NTAGS + j] : 0.f;

    float alpha = (j < NTAGS) ? (logits[(size_t)(0 * BB + b) * NTAGS + j] + start_s[j]) : -1e30f;

    for (int t = 1; t < TT; ++t) {
        bool mt = (words[b * TT + t] != 0);
        if (mt) {
            float v[NTAGS];
            float mx = -1e30f;
            #pragma unroll
            for (int i2 = 0; i2 < NTAGS; ++i2) {
                float ai = __shfl(alpha, i2, 64);
                v[i2] = ai + tcol[i2];
                mx = fmaxf(mx, v[i2]);
            }
            float s = 0.f;
            #pragma unroll
            for (int i2 = 0; i2 < NTAGS; ++i2) s += __expf(v[i2] - mx);
            float na = mx + __logf(s) + logits[(size_t)(t * BB + b) * NTAGS + j];
            alpha = (j < NTAGS) ? na : -1e30f;
        }
    }

    // normalizer = logsumexp_j(alpha + end_s)
    float val = (j < NTAGS) ? (alpha + end_s[j]) : -1e30f;
    float mx = val;
    for (int off = 32; off > 0; off >>= 1) mx = fmaxf(mx, __shfl_xor(mx, off, 64));
    float s = (j < NTAGS) ? __expf(val - mx) : 0.f;
    for (int off = 32; off > 0; off >>= 1) s += __shfl_xor(s, off, 64);
    float norm = mx + __logf(s);

    // gold score (lane-parallel over t)
    float gold = 0.f, slen = 0.f;
    for (int t = j; t < TT; t += 64) {
        int tg = target[b * TT + t];
        bool m = (words[b * TT + t] != 0);
        if (m) {
            gold += logits[(size_t)(t * BB + b) * NTAGS + tg];
            slen += 1.f;
            if (t >= 1) gold += trans[target[b * TT + t - 1] * NTAGS + tg];
        }
    }
    for (int off = 32; off > 0; off >>= 1) {
        gold += __shfl_xor(gold, off, 64);
        slen += __shfl_xor(slen, off, 64);
    }
    if (j == 0) {
        int len = (int)slen;
        int last = (len > 0) ? (len - 1) : 0;
        int last_tag = target[b * TT + last];
        gold += start_s[target[b * TT + 0]] + end_s[last_tag];
        out[b] = norm - gold;
    }
}

// ---------------------------------------------------------------------------
extern "C" void kernel_launch(void* const* d_in, const int* in_sizes, int n_in,
                              void* d_out, int out_size, void* d_ws, size_t ws_size,
                              hipStream_t stream) {
    const int*   words   = (const int*)  d_in[0];
    const int*   target  = (const int*)  d_in[1];
    const float* embed   = (const float*)d_in[2];
    const float* in_fc_w = (const float*)d_in[3];
    const float* in_fc_b = (const float*)d_in[4];
    const float* Wih0    = (const float*)d_in[5];
    const float* Whh0    = (const float*)d_in[6];
    const float* bih0    = (const float*)d_in[7];
    const float* bhh0    = (const float*)d_in[8];
    const float* Wih1    = (const float*)d_in[9];
    const float* Whh1    = (const float*)d_in[10];
    const float* bih1    = (const float*)d_in[11];
    const float* bhh1    = (const float*)d_in[12];
    const float* out_w   = (const float*)d_in[13];
    const float* out_b   = (const float*)d_in[14];
    const float* trans   = (const float*)d_in[15];
    const float* start_s = (const float*)d_in[16];
    const float* end_s   = (const float*)d_in[17];
    float* out = (float*)d_out;

    float* ws = (float*)d_ws;
    // layout (floats):
    //   x      : [0, 2097152)                    8192 x 256
    //   pre    : [2097152, 8650752)              8192 x 800 (reused layer0/1)
    //   h0     : [8650752, 10289152)             8192 x 200
    //   h1     : [0, 1638400)                    reuse of x region
    //   logits : [1638400, 1810432)              8192 x 21
    float* x      = ws;
    float* pre    = ws + 2097152;
    float* h0     = ws + 8650752;
    float* h1     = ws;
    float* logits = ws + 1638400;

    // 1) x = gather(embed, words) @ in_fc_w^T + in_fc_b     (8192 x 256)
    gemm_bias<<<dim3(NTOK / 64, DMODEL / 64), 256, 0, stream>>>(
        embed, EMBED, in_fc_w, EMBED, in_fc_b, nullptr,
        x, DMODEL, NTOK, DMODEL, EMBED, words);

    // 2) pre0 = x @ [Wih0_f; Wih0_b]^T + (bih0 + bhh0)      (8192 x 800)
    gemm_bias<<<dim3(NTOK / 64, 13), 256, 0, stream>>>(
        x, DMODEL, Wih0, DMODEL, bih0, bhh0,
        pre, 800, NTOK, 800, DMODEL, nullptr);

    // 3) layer0 recurrence -> h0 (8192 x 200)
    lstm_layer<<<64, 448, 0, stream>>>(pre, Whh0, h0);

    // 4) pre1 = h0 @ [Wih1_f; Wih1_b]^T + (bih1 + bhh1)     (8192 x 800)
    gemm_bias<<<dim3(NTOK / 64, 13), 256, 0, stream>>>(
        h0, 200, Wih1, 200, bih1, bhh1,
        pre, 800, NTOK, 800, 200, nullptr);

    // 5) layer1 recurrence -> h1 (8192 x 200)
    lstm_layer<<<64, 448, 0, stream>>>(pre, Whh1, h1);

    // 6) logits + log_softmax (8192 x 21)
    logits_lsm<<<NTOK / 8, 256, 0, stream>>>(h1, out_w, out_b, logits);

    // 7) CRF loss -> out (32)
    crf_kernel<<<BB, 64, 0, stream>>>(logits, words, target, trans, start_s, end_s, out);
}

// Round 3
// 816.567 us; speedup vs baseline: 1.2775x; 1.2775x over previous
//
#include <hip/hip_runtime.h>
#include <hip/hip_bf16.h>

// Model dims
#define VOCAB 21128
#define EMBED 768
#define DMODEL 256
#define HID 100
#define NTAGS 21
#define BB 32
#define TT 256
#define NTOK (BB*TT)   // 8192 tokens, token index i = t*BB + b

__device__ __forceinline__ float sigm(float x) { return 1.0f / (1.0f + __expf(-x)); }
__device__ __forceinline__ float tanh_(float x) { return 2.0f / (1.0f + __expf(-2.0f * x)) - 1.0f; }

// ---------------------------------------------------------------------------
// Generic SGEMM: C(M x N) = A(M x K) @ B(N x K)^T + bias1 + bias2
// A rows optionally gathered through the embedding: row i -> embed row
// words[(i&31)*TT + (i>>5)].
// Tiles: 64x64, Ktile=8, 256 threads, 4x4 per-thread microtile.
// ---------------------------------------------------------------------------
__global__ __launch_bounds__(256) void gemm_bias(
    const float* __restrict__ A, int lda,
    const float* __restrict__ B, int ldb,
    const float* __restrict__ bias1, const float* __restrict__ bias2,
    float* __restrict__ C, int ldc,
    int M, int N, int K,
    const int* __restrict__ gatherWords)
{
    __shared__ float As[8][64];
    __shared__ float Bs[8][64];
    const int row0 = blockIdx.x * 64;
    const int col0 = blockIdx.y * 64;
    const int tid = threadIdx.x;
    const int tx = tid & 15;        // 0..15 -> cols
    const int ty = tid >> 4;        // 0..15 -> rows
    float acc[4][4] = {};

    for (int k0 = 0; k0 < K; k0 += 8) {
        if (tid < 128) {
            int r = tid >> 1, q = tid & 1;
            int grow = row0 + r;
            const float* ap;
            if (gatherWords) {
                int widx = gatherWords[(grow & 31) * TT + (grow >> 5)];
                ap = A + (size_t)widx * lda;
            } else {
                ap = A + (size_t)grow * lda;
            }
            float4 v = *(const float4*)(ap + k0 + q * 4);
            As[q*4+0][r] = v.x; As[q*4+1][r] = v.y;
            As[q*4+2][r] = v.z; As[q*4+3][r] = v.w;
        } else {
            int f = tid - 128;
            int r = f >> 1, q = f & 1;
            int gcol = col0 + r;
            float4 v = make_float4(0.f, 0.f, 0.f, 0.f);
            if (gcol < N) v = *(const float4*)(B + (size_t)gcol * ldb + k0 + q * 4);
            Bs[q*4+0][r] = v.x; Bs[q*4+1][r] = v.y;
            Bs[q*4+2][r] = v.z; Bs[q*4+3][r] = v.w;
        }
        __syncthreads();
        #pragma unroll
        for (int kk = 0; kk < 8; ++kk) {
            float4 av = *(const float4*)&As[kk][ty * 4];
            float4 bv = *(const float4*)&Bs[kk][tx * 4];
            acc[0][0] += av.x * bv.x; acc[0][1] += av.x * bv.y;
            acc[0][2] += av.x * bv.z; acc[0][3] += av.x * bv.w;
            acc[1][0] += av.y * bv.x; acc[1][1] += av.y * bv.y;
            acc[1][2] += av.y * bv.z; acc[1][3] += av.y * bv.w;
            acc[2][0] += av.z * bv.x; acc[2][1] += av.z * bv.y;
            acc[2][2] += av.z * bv.z; acc[2][3] += av.z * bv.w;
            acc[3][0] += av.w * bv.x; acc[3][1] += av.w * bv.y;
            acc[3][2] += av.w * bv.z; acc[3][3] += av.w * bv.w;
        }
        __syncthreads();
    }

    float bb_[4];
    #pragma unroll
    for (int jj = 0; jj < 4; ++jj) {
        int gcol = col0 + tx * 4 + jj;
        float bv = 0.f;
        if (gcol < N) {
            bv = bias1[gcol];
            if (bias2) bv += bias2[gcol];
        }
        bb_[jj] = bv;
    }
    #pragma unroll
    for (int ii = 0; ii < 4; ++ii) {
        int grow = row0 + ty * 4 + ii;
        #pragma unroll
        for (int jj = 0; jj < 4; ++jj) {
            int gcol = col0 + tx * 4 + jj;
            if (gcol < N) C[(size_t)grow * ldc + gcol] = acc[ii][jj] + bb_[jj];
        }
    }
}

// ---------------------------------------------------------------------------
// LSTM recurrence for one layer, both directions.
// grid = 64 blocks: block = (dir<<5)|b.  448 threads = 7 waves.
// Wave w owns hidden units w*16..w*16+15; lane = q*16 + (unit&15), q = gate.
// Each thread holds one Whh gate-row (100 floats) in 25 float4 REGISTERS.
// pre: (NTOK, 800), gate row g of dir d at [i*800 + d*400 + g] (biases folded).
// Whh: (2, 400, 100).  hout: (NTOK, 200), dir0 -> [0..99], dir1 -> [100..199].
// One barrier per step: h double-buffered in LDS, gate exchange via shfl.
// ---------------------------------------------------------------------------
__global__ __launch_bounds__(448, 1) void lstm_layer(
    const float* __restrict__ pre,
    const float* __restrict__ Whh,
    float* __restrict__ hout)
{
    const int dir = blockIdx.x >> 5;
    const int b = blockIdx.x & 31;
    const int tid = threadIdx.x;
    const int wave = tid >> 6;              // 0..6
    const int lane = tid & 63;
    const int q = lane >> 4;                // gate 0..3 (i,f,g,o)
    const int jj = (wave << 4) | (lane & 15);  // hidden unit 0..111
    const bool act = (jj < HID);

    __shared__ alignas(16) float h_lds[2][112];

    // weight row Whh[dir][q*HID + jj][:] -> 25 float4 registers
    float4 wv[25];
    if (act) {
        const float4* wr = (const float4*)(Whh + ((size_t)dir * 400 + q * HID + jj) * HID);
        #pragma unroll
        for (int k = 0; k < 25; ++k) wv[k] = wr[k];
    } else {
        #pragma unroll
        for (int k = 0; k < 25; ++k) wv[k] = make_float4(0.f, 0.f, 0.f, 0.f);
    }

    float c = 0.f;
    if (tid < 112) { h_lds[0][tid] = 0.f; h_lds[1][tid] = 0.f; }
    __syncthreads();

    const int rowoff = dir * 400 + q * HID + jj;
    const int t0 = dir ? (TT - 1) : 0;
    float pcur = act ? pre[(size_t)(t0 * BB + b) * 800 + rowoff] : 0.f;

    for (int s = 0; s < TT; ++s) {
        const int t = dir ? (TT - 1 - s) : s;
        const int i = t * BB + b;

        // prefetch next step's pre (consumed after the next barrier)
        float pnxt = 0.f;
        if (s + 1 < TT) {
            const int tn = dir ? (TT - 2 - s) : (s + 1);
            if (act) pnxt = pre[(size_t)(tn * BB + b) * 800 + rowoff];
        }

        // matvec: gate = pre + Whh_row . h   (h broadcast from LDS)
        const float* hb = h_lds[s & 1];
        float a0 = 0.f, a1 = 0.f, a2 = 0.f, a3 = 0.f;
        #pragma unroll
        for (int kk = 0; kk < 25; ++kk) {
            float4 hv = *(const float4*)&hb[kk * 4];
            a0 += wv[kk].x * hv.x;
            a1 += wv[kk].y * hv.y;
            a2 += wv[kk].z * hv.z;
            a3 += wv[kk].w * hv.w;
        }
        float g = pcur + ((a0 + a1) + (a2 + a3));

        // collect the 4 gates for this hidden unit into the q==0 lane
        const int base = lane & 15;
        float gi = __shfl(g, base +  0, 64);
        float gf = __shfl(g, base + 16, 64);
        float gg = __shfl(g, base + 32, 64);
        float go = __shfl(g, base + 48, 64);

        if (q == 0 && act) {
            float igt = sigm(gi);
            float fgt = sigm(gf);
            float ggt = tanh_(gg);
            float ogt = sigm(go);
            c = fgt * c + igt * ggt;
            float h = ogt * tanh_(c);
            h_lds[(s + 1) & 1][jj] = h;           // write NEXT buffer (no WAR hazard)
            hout[(size_t)i * 200 + dir * HID + jj] = h;
        }
        __syncthreads();
        pcur = pnxt;
    }
}

// ---------------------------------------------------------------------------
// logits + log_softmax: per token i: l[n] = h1[i] . out_w[n] + out_b[n],
// then l -= logsumexp(l).  One 32-lane half-wave per token.
// ---------------------------------------------------------------------------
__global__ __launch_bounds__(256) void logits_lsm(
    const float* __restrict__ h1,
    const float* __restrict__ out_w,
    const float* __restrict__ out_b,
    float* __restrict__ logits)
{
    const int lane = threadIdx.x & 63;
    const int wid = (blockIdx.x * 256 + threadIdx.x) >> 6;
    const int half = lane >> 5;
    const int n = lane & 31;
    const int i = wid * 2 + half;
    if (i >= NTOK) return;

    float acc = -1e30f;
    if (n < NTAGS) {
        acc = out_b[n];
        const float4* hr = (const float4*)(h1 + (size_t)i * 200);
        const float4* wr = (const float4*)(out_w + (size_t)n * 200);
        #pragma unroll
        for (int e = 0; e < 50; ++e) {
            float4 h4 = hr[e], w4 = wr[e];
            acc += h4.x * w4.x + h4.y * w4.y + h4.z * w4.z + h4.w * w4.w;
        }
    }
    float m = acc;
    for (int off = 16; off > 0; off >>= 1) m = fmaxf(m, __shfl_xor(m, off, 32));
    float ex = (n < NTAGS) ? __expf(acc - m) : 0.f;
    float s = ex;
    for (int off = 16; off > 0; off >>= 1) s += __shfl_xor(s, off, 32);
    if (n < NTAGS) logits[(size_t)i * NTAGS + n] = acc - m - __logf(s);
}

// ---------------------------------------------------------------------------
// CRF loss: one wave per batch element. alpha recursion + normalizer + gold.
// ---------------------------------------------------------------------------
__global__ __launch_bounds__(64) void crf_kernel(
    const float* __restrict__ logits,
    const int* __restrict__ words,
    const int* __restrict__ target,
    const float* __restrict__ trans,
    const float* __restrict__ start_s,
    const float* __restrict__ end_s,
    float* __restrict__ out)
{
    const int b = blockIdx.x;
    const int j = threadIdx.x;

    float tcol[NTAGS];
    #pragma unroll
    for (int i = 0; i < NTAGS; ++i) tcol[i] = (j < NTAGS) ? trans[i * NTAGS + j] : 0.f;

    float alpha = (j < NTAGS) ? (logits[(size_t)(0 * BB + b) * NTAGS + j] + start_s[j]) : -1e30f;

    for (int t = 1; t < TT; ++t) {
        bool mt = (words[b * TT + t] != 0);
        if (mt) {
            float v[NTAGS];
            float mx = -1e30f;
            #pragma unroll
            for (int i2 = 0; i2 < NTAGS; ++i2) {
                float ai = __shfl(alpha, i2, 64);
                v[i2] = ai + tcol[i2];
                mx = fmaxf(mx, v[i2]);
            }
            float s = 0.f;
            #pragma unroll
            for (int i2 = 0; i2 < NTAGS; ++i2) s += __expf(v[i2] - mx);
            float na = mx + __logf(s) + logits[(size_t)(t * BB + b) * NTAGS + j];
            alpha = (j < NTAGS) ? na : -1e30f;
        }
    }

    // normalizer = logsumexp_j(alpha + end_s)
    float val = (j < NTAGS) ? (alpha + end_s[j]) : -1e30f;
    float mx = val;
    for (int off = 32; off > 0; off >>= 1) mx = fmaxf(mx, __shfl_xor(mx, off, 64));
    float s = (j < NTAGS) ? __expf(val - mx) : 0.f;
    for (int off = 32; off > 0; off >>= 1) s += __shfl_xor(s, off, 64);
    float norm = mx + __logf(s);

    // gold score (lane-parallel over t)
    float gold = 0.f, slen = 0.f;
    for (int t = j; t < TT; t += 64) {
        int tg = target[b * TT + t];
        bool m = (words[b * TT + t] != 0);
        if (m) {
            gold += logits[(size_t)(t * BB + b) * NTAGS + tg];
            slen += 1.f;
            if (t >= 1) gold += trans[target[b * TT + t - 1] * NTAGS + tg];
        }
    }
    for (int off = 32; off > 0; off >>= 1) {
        gold += __shfl_xor(gold, off, 64);
        slen += __shfl_xor(slen, off, 64);
    }
    if (j == 0) {
        int len = (int)slen;
        int last = (len > 0) ? (len - 1) : 0;
        int last_tag = target[b * TT + last];
        gold += start_s[target[b * TT + 0]] + end_s[last_tag];
        out[b] = norm - gold;
    }
}

// ---------------------------------------------------------------------------
extern "C" void kernel_launch(void* const* d_in, const int* in_sizes, int n_in,
                              void* d_out, int out_size, void* d_ws, size_t ws_size,
                              hipStream_t stream) {
    const int*   words   = (const int*)  d_in[0];
    const int*   target  = (const int*)  d_in[1];
    const float* embed   = (const float*)d_in[2];
    const float* in_fc_w = (const float*)d_in[3];
    const float* in_fc_b = (const float*)d_in[4];
    const float* Wih0    = (const float*)d_in[5];
    const float* Whh0    = (const float*)d_in[6];
    const float* bih0    = (const float*)d_in[7];
    const float* bhh0    = (const float*)d_in[8];
    const float* Wih1    = (const float*)d_in[9];
    const float* Whh1    = (const float*)d_in[10];
    const float* bih1    = (const float*)d_in[11];
    const float* bhh1    = (const float*)d_in[12];
    const float* out_w   = (const float*)d_in[13];
    const float* out_b   = (const float*)d_in[14];
    const float* trans   = (const float*)d_in[15];
    const float* start_s = (const float*)d_in[16];
    const float* end_s   = (const float*)d_in[17];
    float* out = (float*)d_out;

    float* ws = (float*)d_ws;
    // layout (floats):
    //   x      : [0, 2097152)                    8192 x 256
    //   pre    : [2097152, 8650752)              8192 x 800 (reused layer0/1)
    //   h0     : [8650752, 10289152)             8192 x 200
    //   h1     : [0, 1638400)                    reuse of x region
    //   logits : [1638400, 1810432)              8192 x 21
    float* x      = ws;
    float* pre    = ws + 2097152;
    float* h0     = ws + 8650752;
    float* h1     = ws;
    float* logits = ws + 1638400;

    // 1) x = gather(embed, words) @ in_fc_w^T + in_fc_b     (8192 x 256)
    gemm_bias<<<dim3(NTOK / 64, DMODEL / 64), 256, 0, stream>>>(
        embed, EMBED, in_fc_w, EMBED, in_fc_b, nullptr,
        x, DMODEL, NTOK, DMODEL, EMBED, words);

    // 2) pre0 = x @ [Wih0_f; Wih0_b]^T + (bih0 + bhh0)      (8192 x 800)
    gemm_bias<<<dim3(NTOK / 64, 13), 256, 0, stream>>>(
        x, DMODEL, Wih0, DMODEL, bih0, bhh0,
        pre, 800, NTOK, 800, DMODEL, nullptr);

    // 3) layer0 recurrence -> h0 (8192 x 200)
    lstm_layer<<<64, 448, 0, stream>>>(pre, Whh0, h0);

    // 4) pre1 = h0 @ [Wih1_f; Wih1_b]^T + (bih1 + bhh1)     (8192 x 800)
    gemm_bias<<<dim3(NTOK / 64, 13), 256, 0, stream>>>(
        h0, 200, Wih1, 200, bih1, bhh1,
        pre, 800, NTOK, 800, 200, nullptr);

    // 5) layer1 recurrence -> h1 (8192 x 200)
    lstm_layer<<<64, 448, 0, stream>>>(pre, Whh1, h1);

    // 6) logits + log_softmax (8192 x 21)
    logits_lsm<<<NTOK / 8, 256, 0, stream>>>(h1, out_w, out_b, logits);

    // 7) CRF loss -> out (32)
    crf_kernel<<<BB, 64, 0, stream>>>(logits, words, target, trans, start_s, end_s, out);
}

// Round 4
// 811.994 us; speedup vs baseline: 1.2847x; 1.0056x over previous
//
#include <hip/hip_runtime.h>
#include <hip/hip_bf16.h>

// Model dims
#define VOCAB 21128
#define EMBED 768
#define DMODEL 256
#define HID 100
#define NTAGS 21
#define BB 32
#define TT 256
#define NTOK (BB*TT)   // 8192 tokens, token index i = t*BB + b

typedef float f32x4 __attribute__((ext_vector_type(4)));

__device__ __forceinline__ float sigm(float x) { return 1.0f / (1.0f + __expf(-x)); }
__device__ __forceinline__ float tanh_(float x) { return 2.0f / (1.0f + __expf(-2.0f * x)) - 1.0f; }

// ---------------------------------------------------------------------------
// Generic SGEMM: C(M x N) = A(M x K) @ B(N x K)^T + bias1 + bias2
// A rows optionally gathered through the embedding: row i -> embed row
// words[(i&31)*TT + (i>>5)].
// Tiles: 64x64, Ktile=8, 256 threads, 4x4 per-thread microtile.
// ---------------------------------------------------------------------------
__global__ __launch_bounds__(256) void gemm_bias(
    const float* __restrict__ A, int lda,
    const float* __restrict__ B, int ldb,
    const float* __restrict__ bias1, const float* __restrict__ bias2,
    float* __restrict__ C, int ldc,
    int M, int N, int K,
    const int* __restrict__ gatherWords)
{
    __shared__ float As[8][64];
    __shared__ float Bs[8][64];
    const int row0 = blockIdx.x * 64;
    const int col0 = blockIdx.y * 64;
    const int tid = threadIdx.x;
    const int tx = tid & 15;        // 0..15 -> cols
    const int ty = tid >> 4;        // 0..15 -> rows
    float acc[4][4] = {};

    for (int k0 = 0; k0 < K; k0 += 8) {
        if (tid < 128) {
            int r = tid >> 1, q = tid & 1;
            int grow = row0 + r;
            const float* ap;
            if (gatherWords) {
                int widx = gatherWords[(grow & 31) * TT + (grow >> 5)];
                ap = A + (size_t)widx * lda;
            } else {
                ap = A + (size_t)grow * lda;
            }
            float4 v = *(const float4*)(ap + k0 + q * 4);
            As[q*4+0][r] = v.x; As[q*4+1][r] = v.y;
            As[q*4+2][r] = v.z; As[q*4+3][r] = v.w;
        } else {
            int f = tid - 128;
            int r = f >> 1, q = f & 1;
            int gcol = col0 + r;
            float4 v = make_float4(0.f, 0.f, 0.f, 0.f);
            if (gcol < N) v = *(const float4*)(B + (size_t)gcol * ldb + k0 + q * 4);
            Bs[q*4+0][r] = v.x; Bs[q*4+1][r] = v.y;
            Bs[q*4+2][r] = v.z; Bs[q*4+3][r] = v.w;
        }
        __syncthreads();
        #pragma unroll
        for (int kk = 0; kk < 8; ++kk) {
            float4 av = *(const float4*)&As[kk][ty * 4];
            float4 bv = *(const float4*)&Bs[kk][tx * 4];
            acc[0][0] += av.x * bv.x; acc[0][1] += av.x * bv.y;
            acc[0][2] += av.x * bv.z; acc[0][3] += av.x * bv.w;
            acc[1][0] += av.y * bv.x; acc[1][1] += av.y * bv.y;
            acc[1][2] += av.y * bv.z; acc[1][3] += av.y * bv.w;
            acc[2][0] += av.z * bv.x; acc[2][1] += av.z * bv.y;
            acc[2][2] += av.z * bv.z; acc[2][3] += av.z * bv.w;
            acc[3][0] += av.w * bv.x; acc[3][1] += av.w * bv.y;
            acc[3][2] += av.w * bv.z; acc[3][3] += av.w * bv.w;
        }
        __syncthreads();
    }

    float bb_[4];
    #pragma unroll
    for (int jj = 0; jj < 4; ++jj) {
        int gcol = col0 + tx * 4 + jj;
        float bv = 0.f;
        if (gcol < N) {
            bv = bias1[gcol];
            if (bias2) bv += bias2[gcol];
        }
        bb_[jj] = bv;
    }
    #pragma unroll
    for (int ii = 0; ii < 4; ++ii) {
        int grow = row0 + ty * 4 + ii;
        #pragma unroll
        for (int jj = 0; jj < 4; ++jj) {
            int gcol = col0 + tx * 4 + jj;
            if (gcol < N) C[(size_t)grow * ldc + gcol] = acc[ii][jj] + bb_[jj];
        }
    }
}

// ---------------------------------------------------------------------------
// LSTM recurrence for one layer, both directions.
// grid = 64 blocks: block = (dir<<5)|b.  448 threads = 7 waves.
// Wave w owns hidden units w*16..w*16+15; lane = q*16 + (unit&15), q = gate.
// Each thread holds one Whh gate-row (100 floats) in 25 float4 REGISTERS,
// pinned via empty inline asm so the compiler cannot sink the loads back
// into the recurrence loop (round-3 evidence: VGPR=68 -> weights were
// re-fetched from L2 every step, 2200 cyc/step latency-bound).
// ---------------------------------------------------------------------------
__global__ __launch_bounds__(448, 1) void lstm_layer(
    const float* __restrict__ pre,
    const float* __restrict__ Whh,
    float* __restrict__ hout)
{
    const int dir = blockIdx.x >> 5;
    const int b = blockIdx.x & 31;
    const int tid = threadIdx.x;
    const int wave = tid >> 6;              // 0..6
    const int lane = tid & 63;
    const int q = lane >> 4;                // gate 0..3 (i,f,g,o)
    const int jj = (wave << 4) | (lane & 15);  // hidden unit 0..111
    const bool act = (jj < HID);
    const int jc = act ? jj : (HID - 1);    // clamped row (uniform load, in-bounds)

    __shared__ alignas(16) float h_lds[2][112];

    // weight row Whh[dir][q*HID + jc][:] -> 25 float4 registers, pinned
    f32x4 wv[25];
    {
        const f32x4* wr = (const f32x4*)(Whh + ((size_t)dir * 400 + q * HID + jc) * HID);
        #pragma unroll
        for (int k = 0; k < 25; ++k) wv[k] = wr[k];
        #pragma unroll
        for (int k = 0; k < 25; ++k) asm volatile("" : "+v"(wv[k]));
    }

    float c = 0.f;
    if (tid < 112) { h_lds[0][tid] = 0.f; h_lds[1][tid] = 0.f; }
    __syncthreads();

    const int rowoff = dir * 400 + q * HID + jj;
    const int t0 = dir ? (TT - 1) : 0;
    float pcur = act ? pre[(size_t)(t0 * BB + b) * 800 + rowoff] : 0.f;

    for (int s = 0; s < TT; ++s) {
        const int t = dir ? (TT - 1 - s) : s;
        const int i = t * BB + b;

        // prefetch next step's pre (consumed after the next barrier)
        float pnxt = 0.f;
        if (s + 1 < TT) {
            const int tn = dir ? (TT - 2 - s) : (s + 1);
            if (act) pnxt = pre[(size_t)(tn * BB + b) * 800 + rowoff];
        }

        // matvec: gate = pre + Whh_row . h   (h broadcast from LDS)
        const float* hb = h_lds[s & 1];
        float a0 = 0.f, a1 = 0.f, a2 = 0.f, a3 = 0.f;
        #pragma unroll
        for (int kk = 0; kk < 25; ++kk) {
            f32x4 hv = *(const f32x4*)&hb[kk * 4];
            a0 += wv[kk].x * hv.x;
            a1 += wv[kk].y * hv.y;
            a2 += wv[kk].z * hv.z;
            a3 += wv[kk].w * hv.w;
        }
        float g = pcur + ((a0 + a1) + (a2 + a3));

        // collect the 4 gates for this hidden unit into the q==0 lane
        const int base = lane & 15;
        float gi = __shfl(g, base +  0, 64);
        float gf = __shfl(g, base + 16, 64);
        float gg = __shfl(g, base + 32, 64);
        float go = __shfl(g, base + 48, 64);

        if (q == 0 && act) {
            float igt = sigm(gi);
            float fgt = sigm(gf);
            float ggt = tanh_(gg);
            float ogt = sigm(go);
            c = fgt * c + igt * ggt;
            float h = ogt * tanh_(c);
            h_lds[(s + 1) & 1][jj] = h;           // write NEXT buffer (no WAR hazard)
            hout[(size_t)i * 200 + dir * HID + jj] = h;
        }
        __syncthreads();
        pcur = pnxt;
    }
}

// ---------------------------------------------------------------------------
// logits + log_softmax: per token i: l[n] = h1[i] . out_w[n] + out_b[n],
// then l -= logsumexp(l).  One 32-lane half-wave per token.
// ---------------------------------------------------------------------------
__global__ __launch_bounds__(256) void logits_lsm(
    const float* __restrict__ h1,
    const float* __restrict__ out_w,
    const float* __restrict__ out_b,
    float* __restrict__ logits)
{
    const int lane = threadIdx.x & 63;
    const int wid = (blockIdx.x * 256 + threadIdx.x) >> 6;
    const int half = lane >> 5;
    const int n = lane & 31;
    const int i = wid * 2 + half;
    if (i >= NTOK) return;

    float acc = -1e30f;
    if (n < NTAGS) {
        acc = out_b[n];
        const float4* hr = (const float4*)(h1 + (size_t)i * 200);
        const float4* wr = (const float4*)(out_w + (size_t)n * 200);
        #pragma unroll
        for (int e = 0; e < 50; ++e) {
            float4 h4 = hr[e], w4 = wr[e];
            acc += h4.x * w4.x + h4.y * w4.y + h4.z * w4.z + h4.w * w4.w;
        }
    }
    float m = acc;
    for (int off = 16; off > 0; off >>= 1) m = fmaxf(m, __shfl_xor(m, off, 32));
    float ex = (n < NTAGS) ? __expf(acc - m) : 0.f;
    float s = ex;
    for (int off = 16; off > 0; off >>= 1) s += __shfl_xor(s, off, 32);
    if (n < NTAGS) logits[(size_t)i * NTAGS + n] = acc - m - __logf(s);
}

// ---------------------------------------------------------------------------
// CRF loss: one wave per batch element. alpha recursion + normalizer + gold.
// ---------------------------------------------------------------------------
__global__ __launch_bounds__(64) void crf_kernel(
    const float* __restrict__ logits,
    const int* __restrict__ words,
    const int* __restrict__ target,
    const float* __restrict__ trans,
    const float* __restrict__ start_s,
    const float* __restrict__ end_s,
    float* __restrict__ out)
{
    const int b = blockIdx.x;
    const int j = threadIdx.x;

    float tcol[NTAGS];
    #pragma unroll
    for (int i = 0; i < NTAGS; ++i) tcol[i] = (j < NTAGS) ? trans[i * NTAGS + j] : 0.f;

    float alpha = (j < NTAGS) ? (logits[(size_t)(0 * BB + b) * NTAGS + j] + start_s[j]) : -1e30f;

    for (int t = 1; t < TT; ++t) {
        bool mt = (words[b * TT + t] != 0);
        if (mt) {
            float v[NTAGS];
            float mx = -1e30f;
            #pragma unroll
            for (int i2 = 0; i2 < NTAGS; ++i2) {
                float ai = __shfl(alpha, i2, 64);
                v[i2] = ai + tcol[i2];
                mx = fmaxf(mx, v[i2]);
            }
            float s = 0.f;
            #pragma unroll
            for (int i2 = 0; i2 < NTAGS; ++i2) s += __expf(v[i2] - mx);
            float na = mx + __logf(s) + logits[(size_t)(t * BB + b) * NTAGS + j];
            alpha = (j < NTAGS) ? na : -1e30f;
        }
    }

    // normalizer = logsumexp_j(alpha + end_s)
    float val = (j < NTAGS) ? (alpha + end_s[j]) : -1e30f;
    float mx = val;
    for (int off = 32; off > 0; off >>= 1) mx = fmaxf(mx, __shfl_xor(mx, off, 64));
    float s = (j < NTAGS) ? __expf(val - mx) : 0.f;
    for (int off = 32; off > 0; off >>= 1) s += __shfl_xor(s, off, 64);
    float norm = mx + __logf(s);

    // gold score (lane-parallel over t)
    float gold = 0.f, slen = 0.f;
    for (int t = j; t < TT; t += 64) {
        int tg = target[b * TT + t];
        bool m = (words[b * TT + t] != 0);
        if (m) {
            gold += logits[(size_t)(t * BB + b) * NTAGS + tg];
            slen += 1.f;
            if (t >= 1) gold += trans[target[b * TT + t - 1] * NTAGS + tg];
        }
    }
    for (int off = 32; off > 0; off >>= 1) {
        gold += __shfl_xor(gold, off, 64);
        slen += __shfl_xor(slen, off, 64);
    }
    if (j == 0) {
        int len = (int)slen;
        int last = (len > 0) ? (len - 1) : 0;
        int last_tag = target[b * TT + last];
        gold += start_s[target[b * TT + 0]] + end_s[last_tag];
        out[b] = norm - gold;
    }
}

// ---------------------------------------------------------------------------
extern "C" void kernel_launch(void* const* d_in, const int* in_sizes, int n_in,
                              void* d_out, int out_size, void* d_ws, size_t ws_size,
                              hipStream_t stream) {
    const int*   words   = (const int*)  d_in[0];
    const int*   target  = (const int*)  d_in[1];
    const float* embed   = (const float*)d_in[2];
    const float* in_fc_w = (const float*)d_in[3];
    const float* in_fc_b = (const float*)d_in[4];
    const float* Wih0    = (const float*)d_in[5];
    const float* Whh0    = (const float*)d_in[6];
    const float* bih0    = (const float*)d_in[7];
    const float* bhh0    = (const float*)d_in[8];
    const float* Wih1    = (const float*)d_in[9];
    const float* Whh1    = (const float*)d_in[10];
    const float* bih1    = (const float*)d_in[11];
    const float* bhh1    = (const float*)d_in[12];
    const float* out_w   = (const float*)d_in[13];
    const float* out_b   = (const float*)d_in[14];
    const float* trans   = (const float*)d_in[15];
    const float* start_s = (const float*)d_in[16];
    const float* end_s   = (const float*)d_in[17];
    float* out = (float*)d_out;

    float* ws = (float*)d_ws;
    // layout (floats):
    //   x      : [0, 2097152)                    8192 x 256
    //   pre    : [2097152, 8650752)              8192 x 800 (reused layer0/1)
    //   h0     : [8650752, 10289152)             8192 x 200
    //   h1     : [0, 1638400)                    reuse of x region
    //   logits : [1638400, 1810432)              8192 x 21
    float* x      = ws;
    float* pre    = ws + 2097152;
    float* h0     = ws + 8650752;
    float* h1     = ws;
    float* logits = ws + 1638400;

    // 1) x = gather(embed, words) @ in_fc_w^T + in_fc_b     (8192 x 256)
    gemm_bias<<<dim3(NTOK / 64, DMODEL / 64), 256, 0, stream>>>(
        embed, EMBED, in_fc_w, EMBED, in_fc_b, nullptr,
        x, DMODEL, NTOK, DMODEL, EMBED, words);

    // 2) pre0 = x @ [Wih0_f; Wih0_b]^T + (bih0 + bhh0)      (8192 x 800)
    gemm_bias<<<dim3(NTOK / 64, 13), 256, 0, stream>>>(
        x, DMODEL, Wih0, DMODEL, bih0, bhh0,
        pre, 800, NTOK, 800, DMODEL, nullptr);

    // 3) layer0 recurrence -> h0 (8192 x 200)
    lstm_layer<<<64, 448, 0, stream>>>(pre, Whh0, h0);

    // 4) pre1 = h0 @ [Wih1_f; Wih1_b]^T + (bih1 + bhh1)     (8192 x 800)
    gemm_bias<<<dim3(NTOK / 64, 13), 256, 0, stream>>>(
        h0, 200, Wih1, 200, bih1, bhh1,
        pre, 800, NTOK, 800, 200, nullptr);

    // 5) layer1 recurrence -> h1 (8192 x 200)
    lstm_layer<<<64, 448, 0, stream>>>(pre, Whh1, h1);

    // 6) logits + log_softmax (8192 x 21)
    logits_lsm<<<NTOK / 8, 256, 0, stream>>>(h1, out_w, out_b, logits);

    // 7) CRF loss -> out (32)
    crf_kernel<<<BB, 64, 0, stream>>>(logits, words, target, trans, start_s, end_s, out);
}